// Round 4
// baseline (1028.356 us; speedup 1.0000x reference)
//
#include <hip/hip_runtime.h>

typedef __attribute__((ext_vector_type(8))) short bf16x8;
typedef __attribute__((ext_vector_type(4))) float f32x4;
typedef __attribute__((ext_vector_type(4))) unsigned short u16x4;

#define MFMA __builtin_amdgcn_mfma_f32_16x16x32_bf16

__device__ __forceinline__ unsigned short f2bf(float x) {
    union { float f; unsigned u; } v; v.f = x;
    unsigned r = v.u + 0x7FFFu + ((v.u >> 16) & 1u);
    return (unsigned short)(r >> 16);
}
__device__ __forceinline__ float bf2f(unsigned short h) {
    union { unsigned u; float f; } v; v.u = ((unsigned)h) << 16;
    return v.f;
}

// ===========================================================================
// NEW-PATH pack: B-fragment layout, bf16 hi/lo.
// Regions (shorts): pkc_h(64*512) pkc_l | pkm_h(32*512) pkm_l |
//                   pk1b_h(96*512) pk1b_l | pk2a_h(32*512) pk2a_l |
//                   pk2b_h(32*512) pk2b_l        (total 512*512 shorts)
// pkc: B_cat(128K x 256N): n<128 -> w1a[k][n] (top), else w1a[256+k][n-128] (bot)
// pkm: W_mid(128K x 128N) = w1a[128+k][n]
// ===========================================================================
__global__ void pack_new(const float* __restrict__ w1a, const float* __restrict__ w1b,
                         const float* __restrict__ w2a, const float* __restrict__ w2b,
                         unsigned short* __restrict__ pk)
{
    const int b = blockIdx.x, l = threadIdx.x;
    unsigned short* ph;
    unsigned short* pl;
    int tile;
    bf16x8 hv, lv;

    if (b < 64) {            // cat: 4kc x 16ct
        tile = b;
        ph = pk; pl = pk + 64 * 512;
        int kc = tile >> 4, ct = tile & 15;
#pragma unroll
        for (int j = 0; j < 8; ++j) {
            int k = kc * 32 + (l >> 4) * 8 + j;
            int n = ct * 16 + (l & 15);
            float v = (n < 128) ? w1a[(size_t)k * 128 + n]
                                : w1a[(size_t)(256 + k) * 128 + (n - 128)];
            unsigned short h = f2bf(v);
            hv[j] = (short)h; lv[j] = (short)f2bf(v - bf2f(h));
        }
    } else if (b < 96) {     // mid: 4kc x 8ct
        tile = b - 64;
        ph = pk + 2 * 64 * 512; pl = ph + 32 * 512;
        int kc = tile >> 3, ct = tile & 7;
#pragma unroll
        for (int j = 0; j < 8; ++j) {
            int k = kc * 32 + (l >> 4) * 8 + j;
            int n = ct * 16 + (l & 15);
            float v = w1a[(size_t)(128 + k) * 128 + n];
            unsigned short h = f2bf(v);
            hv[j] = (short)h; lv[j] = (short)f2bf(v - bf2f(h));
        }
    } else if (b < 192) {    // w1b: 4kc x 24ct
        tile = b - 96;
        ph = pk + 2 * 64 * 512 + 2 * 32 * 512; pl = ph + 96 * 512;
        int kc = tile / 24, ct = tile % 24;
#pragma unroll
        for (int j = 0; j < 8; ++j) {
            int k = kc * 32 + (l >> 4) * 8 + j;
            int n = ct * 16 + (l & 15);
            float v = w1b[(size_t)k * 384 + n];
            unsigned short h = f2bf(v);
            hv[j] = (short)h; lv[j] = (short)f2bf(v - bf2f(h));
        }
    } else if (b < 224) {    // w2a: 4kc x 8ct
        tile = b - 192;
        ph = pk + 2 * 64 * 512 + 2 * 32 * 512 + 2 * 96 * 512; pl = ph + 32 * 512;
        int kc = tile >> 3, ct = tile & 7;
#pragma unroll
        for (int j = 0; j < 8; ++j) {
            int k = kc * 32 + (l >> 4) * 8 + j;
            int n = ct * 16 + (l & 15);
            float v = w2a[(size_t)k * 128 + n];
            unsigned short h = f2bf(v);
            hv[j] = (short)h; lv[j] = (short)f2bf(v - bf2f(h));
        }
    } else {                 // w2b: 4kc x 8ct
        tile = b - 224;
        ph = pk + 2 * 64 * 512 + 2 * 32 * 512 + 2 * 96 * 512 + 2 * 32 * 512; pl = ph + 32 * 512;
        int kc = tile >> 3, ct = tile & 7;
#pragma unroll
        for (int j = 0; j < 8; ++j) {
            int k = kc * 32 + (l >> 4) * 8 + j;
            int n = ct * 16 + (l & 15);
            float v = w2b[(size_t)k * 128 + n];
            unsigned short h = f2bf(v);
            hv[j] = (short)h; lv[j] = (short)f2bf(v - bf2f(h));
        }
    }
    *(bf16x8*)&ph[(size_t)(tile * 64 + l) * 8] = hv;
    *(bf16x8*)&pl[(size_t)(tile * 64 + l) * 8] = lv;
}

// ===========================================================================
// Precompute A_tb = obj @ [W_top | W_bot]  (O x 256, f32). Dense, coalesced.
// 512 thr = 8 waves; wave w: rh=w&1 (rows 32rh..), cg=w>>1 (cols 64cg..64cg+63)
// ===========================================================================
__global__ __launch_bounds__(512, 4) void obj_pre_kernel(
    const float* __restrict__ obj,
    const unsigned short* __restrict__ pkc_h, const unsigned short* __restrict__ pkc_l,
    float* __restrict__ A_tb, int O)
{
    __shared__ __align__(16) unsigned short Xh[64 * 128];
    __shared__ __align__(16) unsigned short Xl[64 * 128];

    const int tid = threadIdx.x;
    const int w = tid >> 6, l = tid & 63;
    const int rh = w & 1, cg = w >> 1;
    const int r0 = blockIdx.x * 64;

#pragma unroll
    for (int it = 0; it < 4; ++it) {
        int q = it * 512 + tid;
        int row = q >> 5, c4 = (q & 31) * 4;
        int rg = r0 + row; if (rg > O - 1) rg = O - 1;
        float4 v = *(const float4*)&obj[(size_t)rg * 128 + c4];
        u16x4 hv, lv; unsigned short h;
        h = f2bf(v.x); hv[0] = h; lv[0] = f2bf(v.x - bf2f(h));
        h = f2bf(v.y); hv[1] = h; lv[1] = f2bf(v.y - bf2f(h));
        h = f2bf(v.z); hv[2] = h; lv[2] = f2bf(v.z - bf2f(h));
        h = f2bf(v.w); hv[3] = h; lv[3] = f2bf(v.w - bf2f(h));
        int pc = row * 128 + (c4 ^ ((row & 7) << 3));
        *(u16x4*)&Xh[pc] = hv;
        *(u16x4*)&Xl[pc] = lv;
    }
    __syncthreads();

    f32x4 acc[2][4];
#pragma unroll
    for (int i = 0; i < 2; ++i)
#pragma unroll
        for (int j = 0; j < 4; ++j) acc[i][j] = (f32x4)0.0f;

#pragma unroll
    for (int kc = 0; kc < 4; ++kc) {
        bf16x8 ah[2], al[2];
#pragma unroll
        for (int rt = 0; rt < 2; ++rt) {
            int row = (rh * 2 + rt) * 16 + (l & 15);
            int col0 = kc * 32 + (l >> 4) * 8;
            int pc = row * 128 + (col0 ^ ((row & 7) << 3));
            ah[rt] = *(const bf16x8*)&Xh[pc];
            al[rt] = *(const bf16x8*)&Xl[pc];
        }
#pragma unroll
        for (int ct = 0; ct < 4; ++ct) {
            const int tile = kc * 16 + cg * 4 + ct;
            bf16x8 bh = *(const bf16x8*)&pkc_h[(size_t)(tile * 64 + l) * 8];
            bf16x8 bl = *(const bf16x8*)&pkc_l[(size_t)(tile * 64 + l) * 8];
#pragma unroll
            for (int rt = 0; rt < 2; ++rt) {
                acc[rt][ct] = MFMA(ah[rt], bh, acc[rt][ct], 0, 0, 0);
                acc[rt][ct] = MFMA(ah[rt], bl, acc[rt][ct], 0, 0, 0);
                acc[rt][ct] = MFMA(al[rt], bh, acc[rt][ct], 0, 0, 0);
            }
        }
    }

#pragma unroll
    for (int ct = 0; ct < 4; ++ct) {
        int col = cg * 64 + ct * 16 + (l & 15);
#pragma unroll
        for (int rt = 0; rt < 2; ++rt) {
#pragma unroll
            for (int r = 0; r < 4; ++r) {
                int row = (rh * 2 + rt) * 16 + (l >> 4) * 4 + r;
                if (r0 + row < O)
                    A_tb[(size_t)(r0 + row) * 256 + col] = acc[rt][ct][r];
            }
        }
    }
}

// ===========================================================================
// NEW triple kernel: G = A_top[s]+A_bot[o]+b1a -> acc init; GEMM1 = predi@W_mid
// (K=128 only); GEMM2 + scatter unchanged. LDS: union{G[64][132] f32 | Xh,Xl}.
// ===========================================================================
__global__ __launch_bounds__(512, 4) void triple_mlp_mfma2(
    const float* __restrict__ A_tb, const float* __restrict__ predi,
    const int* __restrict__ edges,
    const float* __restrict__ b1a, const float* __restrict__ b1b,
    const unsigned short* __restrict__ pkm_h, const unsigned short* __restrict__ pkm_l,
    const unsigned short* __restrict__ pk1b_h, const unsigned short* __restrict__ pk1b_l,
    float* __restrict__ pooled, float* __restrict__ out_p,
    float* __restrict__ counts, int T)
{
    __shared__ __align__(16) char SB[64 * 132 * 4];
    float (*G)[132] = (float (*)[132])SB;
    unsigned short* Xh = (unsigned short*)SB;
    unsigned short* Xl = (unsigned short*)(SB + 64 * 128 * 2);
    __shared__ int sIdx[64], oIdx[64];

    const int tid = threadIdx.x;
    const int w = tid >> 6, l = tid & 63;
    const int rh = w & 1, cg = w >> 1;
    const int t0 = blockIdx.x * 64;

    if (tid < 64) {
        int t = t0 + tid; int tc = (t < T) ? t : (T - 1);
        sIdx[tid] = edges[2 * tc];
        oIdx[tid] = edges[2 * tc + 1];
    }
    __syncthreads();

    if (tid < 64)        { if (t0 + tid      < T) atomicAdd(&counts[sIdx[tid]],      1.0f); }
    else if (tid < 128)  { if (t0 + tid - 64 < T) atomicAdd(&counts[oIdx[tid - 64]], 1.0f); }

    // ---- stage G = A_top[s] + A_bot[o] + b1a (f32, pad 132) ----
#pragma unroll
    for (int it = 0; it < 4; ++it) {
        int q = it * 512 + tid;
        int row = q >> 5, c4 = (q & 31) * 4;
        float4 a = *(const float4*)&A_tb[(size_t)sIdx[row] * 256 + c4];
        float4 b = *(const float4*)&A_tb[(size_t)oIdx[row] * 256 + 128 + c4];
        float4 bb = *(const float4*)&b1a[c4];
        float4 g;
        g.x = a.x + b.x + bb.x; g.y = a.y + b.y + bb.y;
        g.z = a.z + b.z + bb.z; g.w = a.w + b.w + bb.w;
        *(float4*)&G[row][c4] = g;
    }
    __syncthreads();

    // ---- init acc1 from G (C-fragment layout) ----
    f32x4 acc1[2][2];
#pragma unroll
    for (int rt = 0; rt < 2; ++rt)
#pragma unroll
        for (int c2 = 0; c2 < 2; ++c2) {
            int col = cg * 32 + c2 * 16 + (l & 15);
#pragma unroll
            for (int r = 0; r < 4; ++r) {
                int row = (rh * 2 + rt) * 16 + (l >> 4) * 4 + r;
                acc1[rt][c2][r] = G[row][col];
            }
        }
    __syncthreads();   // G dead; Xh/Xl reuse the same LDS

    // ---- stage predi rows -> Xh/Xl (bf16 hi/lo, swizzled) ----
#pragma unroll
    for (int it = 0; it < 4; ++it) {
        int q = it * 512 + tid;
        int row = q >> 5, c4 = (q & 31) * 4;
        int t = t0 + row; int tc = (t < T) ? t : (T - 1);
        float4 v = *(const float4*)&predi[(size_t)tc * 128 + c4];
        u16x4 hv, lv; unsigned short h;
        h = f2bf(v.x); hv[0] = h; lv[0] = f2bf(v.x - bf2f(h));
        h = f2bf(v.y); hv[1] = h; lv[1] = f2bf(v.y - bf2f(h));
        h = f2bf(v.z); hv[2] = h; lv[2] = f2bf(v.z - bf2f(h));
        h = f2bf(v.w); hv[3] = h; lv[3] = f2bf(v.w - bf2f(h));
        int pc = row * 128 + (c4 ^ ((row & 7) << 3));
        *(u16x4*)&Xh[pc] = hv;
        *(u16x4*)&Xl[pc] = lv;
    }
    __syncthreads();

    // ---- GEMM1: acc1 += predi @ W_mid (K=128) ----
#pragma unroll
    for (int kc = 0; kc < 4; ++kc) {
        bf16x8 ah[2], al[2];
#pragma unroll
        for (int rt = 0; rt < 2; ++rt) {
            int row = (rh * 2 + rt) * 16 + (l & 15);
            int col0 = kc * 32 + (l >> 4) * 8;
            int pc = row * 128 + (col0 ^ ((row & 7) << 3));
            ah[rt] = *(const bf16x8*)&Xh[pc];
            al[rt] = *(const bf16x8*)&Xl[pc];
        }
#pragma unroll
        for (int c2 = 0; c2 < 2; ++c2) {
            const int tile = kc * 8 + cg * 2 + c2;
            bf16x8 bh = *(const bf16x8*)&pkm_h[(size_t)(tile * 64 + l) * 8];
            bf16x8 bl = *(const bf16x8*)&pkm_l[(size_t)(tile * 64 + l) * 8];
#pragma unroll
            for (int rt = 0; rt < 2; ++rt) {
                acc1[rt][c2] = MFMA(ah[rt], bh, acc1[rt][c2], 0, 0, 0);
                acc1[rt][c2] = MFMA(ah[rt], bl, acc1[rt][c2], 0, 0, 0);
                acc1[rt][c2] = MFMA(al[rt], bh, acc1[rt][c2], 0, 0, 0);
            }
        }
    }
    __syncthreads();   // all GEMM1 reads of Xh/Xl done

    // ---- H = relu(acc1) -> Xh/Xl (bias already folded into G) ----
#pragma unroll
    for (int c2 = 0; c2 < 2; ++c2) {
        int col = cg * 32 + c2 * 16 + (l & 15);
#pragma unroll
        for (int rt = 0; rt < 2; ++rt) {
#pragma unroll
            for (int r = 0; r < 4; ++r) {
                int row = (rh * 2 + rt) * 16 + (l >> 4) * 4 + r;
                float h = fmaxf(acc1[rt][c2][r], 0.0f);
                unsigned short hh = f2bf(h);
                unsigned short hl = f2bf(h - bf2f(hh));
                int pc = row * 128 + (col ^ ((row & 7) << 3));
                Xh[pc] = hh; Xl[pc] = hl;
            }
        }
    }
    __syncthreads();

    // ---- GEMM2: H(64x128) @ w1b(128x384) ----
    f32x4 acc2[2][6];
#pragma unroll
    for (int i = 0; i < 2; ++i)
#pragma unroll
        for (int j = 0; j < 6; ++j) acc2[i][j] = (f32x4)0.0f;

#pragma unroll
    for (int kc = 0; kc < 4; ++kc) {
        bf16x8 ah[2], al[2];
#pragma unroll
        for (int rt = 0; rt < 2; ++rt) {
            int row = (rh * 2 + rt) * 16 + (l & 15);
            int col0 = kc * 32 + (l >> 4) * 8;
            int pc = row * 128 + (col0 ^ ((row & 7) << 3));
            ah[rt] = *(const bf16x8*)&Xh[pc];
            al[rt] = *(const bf16x8*)&Xl[pc];
        }
#pragma unroll
        for (int ct = 0; ct < 6; ++ct) {
            const int tile = kc * 24 + cg * 6 + ct;
            bf16x8 bh = *(const bf16x8*)&pk1b_h[(size_t)(tile * 64 + l) * 8];
            bf16x8 bl = *(const bf16x8*)&pk1b_l[(size_t)(tile * 64 + l) * 8];
#pragma unroll
            for (int rt = 0; rt < 2; ++rt) {
                acc2[rt][ct] = MFMA(ah[rt], bh, acc2[rt][ct], 0, 0, 0);
                acc2[rt][ct] = MFMA(ah[rt], bl, acc2[rt][ct], 0, 0, 0);
                acc2[rt][ct] = MFMA(al[rt], bh, acc2[rt][ct], 0, 0, 0);
            }
        }
    }

    // ---- epilogue ----
#pragma unroll
    for (int ct = 0; ct < 6; ++ct) {
        int col = cg * 96 + ct * 16 + (l & 15);
        float bb = b1b[col];
#pragma unroll
        for (int rt = 0; rt < 2; ++rt) {
#pragma unroll
            for (int r = 0; r < 4; ++r) {
                int row = (rh * 2 + rt) * 16 + (l >> 4) * 4 + r;
                if (t0 + row >= T) continue;
                float v = fmaxf(acc2[rt][ct][r] + bb, 0.0f);
                if (col < 128)
                    atomicAdd(&pooled[(size_t)sIdx[row] * 128 + col], v);
                else if (col < 256)
                    out_p[(size_t)(t0 + row) * 128 + (col - 128)] = v;
                else
                    atomicAdd(&pooled[(size_t)oIdx[row] * 128 + (col - 256)], v);
            }
        }
    }
}

// ===========================================================================
// Object MLP (shared by both paths). In-place over pooled region of d_out.
// ===========================================================================
__global__ __launch_bounds__(512, 4) void obj_mlp_mfma(
    const float* __restrict__ b2a, const float* __restrict__ b2b,
    const unsigned short* __restrict__ pk2a_h, const unsigned short* __restrict__ pk2a_l,
    const unsigned short* __restrict__ pk2b_h, const unsigned short* __restrict__ pk2b_l,
    float* __restrict__ io, const float* __restrict__ counts, int O)
{
    __shared__ __align__(16) unsigned short Xh[64 * 128];
    __shared__ __align__(16) unsigned short Xl[64 * 128];

    const int tid = threadIdx.x;
    const int w = tid >> 6, l = tid & 63;
    const int rh = w & 1, cg = w >> 1;
    const int r0 = blockIdx.x * 64;

#pragma unroll
    for (int it = 0; it < 4; ++it) {
        int q = it * 512 + tid;
        int row = q >> 5, c4 = (q & 31) * 4;
        int rg = r0 + row; if (rg > O - 1) rg = O - 1;
        float c = counts[rg];
        c = fminf(fmaxf(c, 1.0f), 1000.0f);
        float inv = 1.0f / c;
        float4 v = *(const float4*)&io[(size_t)rg * 128 + c4];
        v.x *= inv; v.y *= inv; v.z *= inv; v.w *= inv;
        u16x4 hv, lv; unsigned short h;
        h = f2bf(v.x); hv[0] = h; lv[0] = f2bf(v.x - bf2f(h));
        h = f2bf(v.y); hv[1] = h; lv[1] = f2bf(v.y - bf2f(h));
        h = f2bf(v.z); hv[2] = h; lv[2] = f2bf(v.z - bf2f(h));
        h = f2bf(v.w); hv[3] = h; lv[3] = f2bf(v.w - bf2f(h));
        int pc = row * 128 + (c4 ^ ((row & 7) << 3));
        *(u16x4*)&Xh[pc] = hv;
        *(u16x4*)&Xl[pc] = lv;
    }
    __syncthreads();

    f32x4 acc[2][2];
#pragma unroll
    for (int i = 0; i < 2; ++i) { acc[i][0] = (f32x4)0.0f; acc[i][1] = (f32x4)0.0f; }

#pragma unroll
    for (int kc = 0; kc < 4; ++kc) {
        bf16x8 ah[2], al[2];
#pragma unroll
        for (int rt = 0; rt < 2; ++rt) {
            int row = (rh * 2 + rt) * 16 + (l & 15);
            int col0 = kc * 32 + (l >> 4) * 8;
            int pc = row * 128 + (col0 ^ ((row & 7) << 3));
            ah[rt] = *(const bf16x8*)&Xh[pc];
            al[rt] = *(const bf16x8*)&Xl[pc];
        }
#pragma unroll
        for (int c2 = 0; c2 < 2; ++c2) {
            const int tile = kc * 8 + cg * 2 + c2;
            bf16x8 bh = *(const bf16x8*)&pk2a_h[(size_t)(tile * 64 + l) * 8];
            bf16x8 bl = *(const bf16x8*)&pk2a_l[(size_t)(tile * 64 + l) * 8];
#pragma unroll
            for (int rt = 0; rt < 2; ++rt) {
                acc[rt][c2] = MFMA(ah[rt], bh, acc[rt][c2], 0, 0, 0);
                acc[rt][c2] = MFMA(ah[rt], bl, acc[rt][c2], 0, 0, 0);
                acc[rt][c2] = MFMA(al[rt], bh, acc[rt][c2], 0, 0, 0);
            }
        }
    }
    __syncthreads();

#pragma unroll
    for (int c2 = 0; c2 < 2; ++c2) {
        int col = cg * 32 + c2 * 16 + (l & 15);
        float bb = b2a[col];
#pragma unroll
        for (int rt = 0; rt < 2; ++rt) {
#pragma unroll
            for (int r = 0; r < 4; ++r) {
                int row = (rh * 2 + rt) * 16 + (l >> 4) * 4 + r;
                float h = fmaxf(acc[rt][c2][r] + bb, 0.0f);
                unsigned short hh = f2bf(h);
                unsigned short hl = f2bf(h - bf2f(hh));
                int pc = row * 128 + (col ^ ((row & 7) << 3));
                Xh[pc] = hh; Xl[pc] = hl;
            }
        }
    }
    __syncthreads();

    f32x4 acc2[2][2];
#pragma unroll
    for (int i = 0; i < 2; ++i) { acc2[i][0] = (f32x4)0.0f; acc2[i][1] = (f32x4)0.0f; }

#pragma unroll
    for (int kc = 0; kc < 4; ++kc) {
        bf16x8 ah[2], al[2];
#pragma unroll
        for (int rt = 0; rt < 2; ++rt) {
            int row = (rh * 2 + rt) * 16 + (l & 15);
            int col0 = kc * 32 + (l >> 4) * 8;
            int pc = row * 128 + (col0 ^ ((row & 7) << 3));
            ah[rt] = *(const bf16x8*)&Xh[pc];
            al[rt] = *(const bf16x8*)&Xl[pc];
        }
#pragma unroll
        for (int c2 = 0; c2 < 2; ++c2) {
            const int tile = kc * 8 + cg * 2 + c2;
            bf16x8 bh = *(const bf16x8*)&pk2b_h[(size_t)(tile * 64 + l) * 8];
            bf16x8 bl = *(const bf16x8*)&pk2b_l[(size_t)(tile * 64 + l) * 8];
#pragma unroll
            for (int rt = 0; rt < 2; ++rt) {
                acc2[rt][c2] = MFMA(ah[rt], bh, acc2[rt][c2], 0, 0, 0);
                acc2[rt][c2] = MFMA(ah[rt], bl, acc2[rt][c2], 0, 0, 0);
                acc2[rt][c2] = MFMA(al[rt], bh, acc2[rt][c2], 0, 0, 0);
            }
        }
    }

#pragma unroll
    for (int c2 = 0; c2 < 2; ++c2) {
        int col = cg * 32 + c2 * 16 + (l & 15);
        float bb = b2b[col];
#pragma unroll
        for (int rt = 0; rt < 2; ++rt) {
#pragma unroll
            for (int r = 0; r < 4; ++r) {
                int row = (rh * 2 + rt) * 16 + (l >> 4) * 4 + r;
                if (r0 + row >= O) continue;
                float v = fmaxf(acc2[rt][c2][r] + bb, 0.0f);
                io[(size_t)(r0 + row) * 128 + col] = v;
            }
        }
    }
}

// ===========================================================================
// FALLBACK (R3) pack + triple kernel, used only if ws_size is too small.
// ===========================================================================
__global__ void pack_weights(const float* __restrict__ w1a, const float* __restrict__ w1b,
                             const float* __restrict__ w2a, const float* __restrict__ w2b,
                             unsigned short* __restrict__ pk)
{
    const int b = blockIdx.x, l = threadIdx.x;
    const float* W; int N, tile; unsigned short *ph, *pl;
    if (b < 96)       { W = w1a; N = 128; tile = b;       ph = pk;                 pl = pk + 96*512; }
    else if (b < 192) { W = w1b; N = 384; tile = b - 96;  ph = pk + 2*96*512;      pl = pk + 3*96*512; }
    else if (b < 224) { W = w2a; N = 128; tile = b - 192; ph = pk + 4*96*512;      pl = pk + 4*96*512 + 32*512; }
    else              { W = w2b; N = 128; tile = b - 224; ph = pk + 4*96*512 + 2*32*512; pl = pk + 4*96*512 + 3*32*512; }
    const int tpr = N / 16;
    const int kc = tile / tpr, ct = tile % tpr;
    bf16x8 hv, lv;
#pragma unroll
    for (int j = 0; j < 8; ++j) {
        int k = kc * 32 + (l >> 4) * 8 + j;
        int n = ct * 16 + (l & 15);
        float v = W[(size_t)k * N + n];
        unsigned short h = f2bf(v);
        hv[j] = (short)h;
        lv[j] = (short)f2bf(v - bf2f(h));
    }
    *(bf16x8*)&ph[(size_t)(tile * 64 + l) * 8] = hv;
    *(bf16x8*)&pl[(size_t)(tile * 64 + l) * 8] = lv;
}

__global__ __launch_bounds__(512, 4) void triple_mlp_mfma(
    const float* __restrict__ obj, const float* __restrict__ predi,
    const int* __restrict__ edges,
    const float* __restrict__ b1a, const float* __restrict__ b1b,
    const unsigned short* __restrict__ pk1a_h, const unsigned short* __restrict__ pk1a_l,
    const unsigned short* __restrict__ pk1b_h, const unsigned short* __restrict__ pk1b_l,
    float* __restrict__ pooled, float* __restrict__ out_p,
    float* __restrict__ counts, int T)
{
    __shared__ __align__(16) unsigned short Xh[64 * 128];
    __shared__ __align__(16) unsigned short Xl[64 * 128];
    __shared__ int sIdx[64], oIdx[64];

    const int tid = threadIdx.x;
    const int w = tid >> 6, l = tid & 63;
    const int rh = w & 1, cg = w >> 1;
    const int t0 = blockIdx.x * 64;

    if (tid < 64) {
        int t = t0 + tid; int tc = (t < T) ? t : (T - 1);
        sIdx[tid] = edges[2 * tc];
        oIdx[tid] = edges[2 * tc + 1];
    }
    __syncthreads();

    if (tid < 64)        { if (t0 + tid      < T) atomicAdd(&counts[sIdx[tid]],      1.0f); }
    else if (tid < 128)  { if (t0 + tid - 64 < T) atomicAdd(&counts[oIdx[tid - 64]], 1.0f); }

    f32x4 acc1[2][2];
#pragma unroll
    for (int i = 0; i < 2; ++i) { acc1[i][0] = (f32x4)0.0f; acc1[i][1] = (f32x4)0.0f; }

#pragma unroll
    for (int s = 0; s < 3; ++s) {
#pragma unroll
        for (int it = 0; it < 4; ++it) {
            int q = it * 512 + tid;
            int row = q >> 5, c4 = (q & 31) * 4;
            int t = t0 + row; int tc = (t < T) ? t : (T - 1);
            const float* src = (s == 0) ? obj   + (size_t)sIdx[row] * 128 + c4
                             : (s == 1) ? predi + (size_t)tc        * 128 + c4
                                        : obj   + (size_t)oIdx[row] * 128 + c4;
            float4 v = *(const float4*)src;
            u16x4 hv, lv; unsigned short h;
            h = f2bf(v.x); hv[0] = h; lv[0] = f2bf(v.x - bf2f(h));
            h = f2bf(v.y); hv[1] = h; lv[1] = f2bf(v.y - bf2f(h));
            h = f2bf(v.z); hv[2] = h; lv[2] = f2bf(v.z - bf2f(h));
            h = f2bf(v.w); hv[3] = h; lv[3] = f2bf(v.w - bf2f(h));
            int pc = row * 128 + (c4 ^ ((row & 7) << 3));
            *(u16x4*)&Xh[pc] = hv;
            *(u16x4*)&Xl[pc] = lv;
        }
        __syncthreads();

#pragma unroll
        for (int kc2 = 0; kc2 < 4; ++kc2) {
            const int kcg = s * 4 + kc2;
            bf16x8 ah[2], al[2];
#pragma unroll
            for (int rt = 0; rt < 2; ++rt) {
                int row = (rh * 2 + rt) * 16 + (l & 15);
                int col0 = kc2 * 32 + (l >> 4) * 8;
                int pc = row * 128 + (col0 ^ ((row & 7) << 3));
                ah[rt] = *(const bf16x8*)&Xh[pc];
                al[rt] = *(const bf16x8*)&Xl[pc];
            }
#pragma unroll
            for (int c2 = 0; c2 < 2; ++c2) {
                const int tile = kcg * 8 + cg * 2 + c2;
                bf16x8 bh = *(const bf16x8*)&pk1a_h[(size_t)(tile * 64 + l) * 8];
                bf16x8 bl = *(const bf16x8*)&pk1a_l[(size_t)(tile * 64 + l) * 8];
#pragma unroll
                for (int rt = 0; rt < 2; ++rt) {
                    acc1[rt][c2] = MFMA(ah[rt], bh, acc1[rt][c2], 0, 0, 0);
                    acc1[rt][c2] = MFMA(ah[rt], bl, acc1[rt][c2], 0, 0, 0);
                    acc1[rt][c2] = MFMA(al[rt], bh, acc1[rt][c2], 0, 0, 0);
                }
            }
        }
        __syncthreads();
    }

#pragma unroll
    for (int c2 = 0; c2 < 2; ++c2) {
        int col = cg * 32 + c2 * 16 + (l & 15);
        float bb = b1a[col];
#pragma unroll
        for (int rt = 0; rt < 2; ++rt) {
#pragma unroll
            for (int r = 0; r < 4; ++r) {
                int row = (rh * 2 + rt) * 16 + (l >> 4) * 4 + r;
                float h = fmaxf(acc1[rt][c2][r] + bb, 0.0f);
                unsigned short hh = f2bf(h);
                unsigned short hl = f2bf(h - bf2f(hh));
                int pc = row * 128 + (col ^ ((row & 7) << 3));
                Xh[pc] = hh; Xl[pc] = hl;
            }
        }
    }
    __syncthreads();

    f32x4 acc2[2][6];
#pragma unroll
    for (int i = 0; i < 2; ++i)
#pragma unroll
        for (int j = 0; j < 6; ++j) acc2[i][j] = (f32x4)0.0f;

#pragma unroll
    for (int kc = 0; kc < 4; ++kc) {
        bf16x8 ah[2], al[2];
#pragma unroll
        for (int rt = 0; rt < 2; ++rt) {
            int row = (rh * 2 + rt) * 16 + (l & 15);
            int col0 = kc * 32 + (l >> 4) * 8;
            int pc = row * 128 + (col0 ^ ((row & 7) << 3));
            ah[rt] = *(const bf16x8*)&Xh[pc];
            al[rt] = *(const bf16x8*)&Xl[pc];
        }
#pragma unroll
        for (int ct = 0; ct < 6; ++ct) {
            const int tile = kc * 24 + cg * 6 + ct;
            bf16x8 bh = *(const bf16x8*)&pk1b_h[(size_t)(tile * 64 + l) * 8];
            bf16x8 bl = *(const bf16x8*)&pk1b_l[(size_t)(tile * 64 + l) * 8];
#pragma unroll
            for (int rt = 0; rt < 2; ++rt) {
                acc2[rt][ct] = MFMA(ah[rt], bh, acc2[rt][ct], 0, 0, 0);
                acc2[rt][ct] = MFMA(ah[rt], bl, acc2[rt][ct], 0, 0, 0);
                acc2[rt][ct] = MFMA(al[rt], bh, acc2[rt][ct], 0, 0, 0);
            }
        }
    }

#pragma unroll
    for (int ct = 0; ct < 6; ++ct) {
        int col = cg * 96 + ct * 16 + (l & 15);
        float bb = b1b[col];
#pragma unroll
        for (int rt = 0; rt < 2; ++rt) {
#pragma unroll
            for (int r = 0; r < 4; ++r) {
                int row = (rh * 2 + rt) * 16 + (l >> 4) * 4 + r;
                if (t0 + row >= T) continue;
                float v = fmaxf(acc2[rt][ct][r] + bb, 0.0f);
                if (col < 128)
                    atomicAdd(&pooled[(size_t)sIdx[row] * 128 + col], v);
                else if (col < 256)
                    out_p[(size_t)(t0 + row) * 128 + (col - 128)] = v;
                else
                    atomicAdd(&pooled[(size_t)oIdx[row] * 128 + (col - 256)], v);
            }
        }
    }
}

extern "C" void kernel_launch(void* const* d_in, const int* in_sizes, int n_in,
                              void* d_out, int out_size, void* d_ws, size_t ws_size,
                              hipStream_t stream) {
    const float* obj   = (const float*)d_in[0];
    const float* predi = (const float*)d_in[1];
    const int*   edges = (const int*)d_in[2];
    const float* w1a   = (const float*)d_in[3];
    const float* b1a   = (const float*)d_in[4];
    const float* w1b   = (const float*)d_in[5];
    const float* b1b   = (const float*)d_in[6];
    const float* w2a   = (const float*)d_in[7];
    const float* b2a   = (const float*)d_in[8];
    const float* w2b   = (const float*)d_in[9];
    const float* b2b   = (const float*)d_in[10];
    (void)n_in; (void)out_size;

    const int O = in_sizes[0] / 128;
    const int T = in_sizes[1] / 128;

    float* out    = (float*)d_out;
    float* pooled = out;
    float* out_p  = out + (size_t)O * 128;
    float* counts = (float*)d_ws;
    unsigned short* pk = (unsigned short*)(counts + O);

    hipMemsetAsync(pooled, 0, (size_t)O * 128 * sizeof(float), stream);
    hipMemsetAsync(counts, 0, (size_t)O * sizeof(float), stream);

    const size_t need = (size_t)O * 4 + (size_t)512 * 512 * 2 + (size_t)O * 256 * 4;

    if (ws_size >= need) {
        // ---- new path ----
        unsigned short* pkc_h  = pk;
        unsigned short* pkc_l  = pkc_h  + 64 * 512;
        unsigned short* pkm_h  = pkc_l  + 64 * 512;
        unsigned short* pkm_l  = pkm_h  + 32 * 512;
        unsigned short* pk1b_h = pkm_l  + 32 * 512;
        unsigned short* pk1b_l = pk1b_h + 96 * 512;
        unsigned short* pk2a_h = pk1b_l + 96 * 512;
        unsigned short* pk2a_l = pk2a_h + 32 * 512;
        unsigned short* pk2b_h = pk2a_l + 32 * 512;
        unsigned short* pk2b_l = pk2b_h + 32 * 512;
        float* A_tb = (float*)(pk + (size_t)512 * 512);

        pack_new<<<256, 64, 0, stream>>>(w1a, w1b, w2a, w2b, pk);
        obj_pre_kernel<<<(O + 63) / 64, 512, 0, stream>>>(obj, pkc_h, pkc_l, A_tb, O);
        triple_mlp_mfma2<<<(T + 63) / 64, 512, 0, stream>>>(
            A_tb, predi, edges, b1a, b1b,
            pkm_h, pkm_l, pk1b_h, pk1b_l,
            pooled, out_p, counts, T);
        obj_mlp_mfma<<<(O + 63) / 64, 512, 0, stream>>>(
            b2a, b2b, pk2a_h, pk2a_l, pk2b_h, pk2b_l, pooled, counts, O);
    } else {
        // ---- fallback (R3) path ----
        unsigned short* pk1a_h = pk;
        unsigned short* pk1a_l = pk1a_h + 96 * 512;
        unsigned short* pk1b_h = pk1a_l + 96 * 512;
        unsigned short* pk1b_l = pk1b_h + 96 * 512;
        unsigned short* pk2a_h = pk1b_l + 96 * 512;
        unsigned short* pk2a_l = pk2a_h + 32 * 512;
        unsigned short* pk2b_h = pk2a_l + 32 * 512;
        unsigned short* pk2b_l = pk2b_h + 32 * 512;

        pack_weights<<<256, 64, 0, stream>>>(w1a, w1b, w2a, w2b, pk);
        triple_mlp_mfma<<<(T + 63) / 64, 512, 0, stream>>>(
            obj, predi, edges, b1a, b1b,
            pk1a_h, pk1a_l, pk1b_h, pk1b_l,
            pooled, out_p, counts, T);
        obj_mlp_mfma<<<(O + 63) / 64, 512, 0, stream>>>(
            b2a, b2b, pk2a_h, pk2a_l, pk2b_h, pk2b_l, pooled, counts, O);
    }
}